// Round 1
// baseline (975.869 us; speedup 1.0000x reference)
//
#include <hip/hip_runtime.h>
#include <hip/hip_bf16.h>

#define Bn 32
#define Sn 2048
#define Dn 1024
#define Hn 8
#define DHn 64
#define DHOn 128
#define ST 128
#define BK 64
#define NKS (Dn / BK)    // 16
#define NTILE (Sn / ST)  // 16

typedef __attribute__((ext_vector_type(8))) short s16x8;
typedef __attribute__((ext_vector_type(4))) short s16x4;
typedef __attribute__((ext_vector_type(4))) float f32x4;

// element-index swizzle for row-major [rows][64] bf16 tiles (breaks the
// 16-way bank conflict of 128B-stride column reads; same XOR on write+read)
__device__ __forceinline__ int swz(int row, int col) {
    return row * 64 + (col ^ ((row & 7) << 3));
}

__device__ __forceinline__ ushort f2bf(float x) {
    union { float f; unsigned int u; } v; v.f = x;
    unsigned int r = v.u + 0x7fffu + ((v.u >> 16) & 1u);
    return (ushort)(r >> 16);
}
__device__ __forceinline__ float bf2f(ushort x) {
    union { unsigned int u; float f; } v; v.u = ((unsigned int)x) << 16; return v.f;
}

// one-time (per launch) weight transpose + bf16 cast into workspace:
// w1t[h][n][k] = bf16(w1[h][k][n]),  w2t[h][o][k] = bf16(w2[h][k][o])
__global__ void prep_w(const float* __restrict__ w1, const float* __restrict__ w2,
                       ushort* __restrict__ w1t, ushort* __restrict__ w2t) {
    int idx = blockIdx.x * 256 + threadIdx.x;
    if (idx < Hn * DHn * Dn) {
        int h = idx / (DHn * Dn);
        int r = idx - h * DHn * Dn;
        int n = r / Dn;
        int k = r - n * Dn;
        w1t[idx] = f2bf(w1[(h * Dn + k) * DHn + n]);
    }
    if (idx < Hn * DHOn * DHn) {
        int h = idx / (DHOn * DHn);
        int r = idx - h * DHOn * DHn;
        int o = r / DHn;
        int k = r - o * DHn;
        w2t[idx] = f2bf(w2[(h * DHn + k) * DHOn + o]);
    }
}

__global__ __launch_bounds__(512, 2)
void attn_pool(const float* __restrict__ feat, const int* __restrict__ mask,
               const ushort* __restrict__ w1t, const ushort* __restrict__ w2t,
               const float* __restrict__ b1, const float* __restrict__ b2,
               float* __restrict__ out) {
    __shared__ ushort a_lds[ST * 64];        // feat tile [s][k], swizzled
    __shared__ ushort b_lds[64 * 64];        // w1 tile [n][k], swizzled
    __shared__ ushort h_lds[ST * 64];        // gelu(h) [s][n], swizzled
    __shared__ ushort w2_lds[DHOn * 64];     // w2 [o][k], swizzled
    __shared__ ushort pool_lds[ST * 132];    // feat slice for pooling [s][o], padded
    __shared__ int    mask_lds[ST];
    __shared__ float  b1_lds[DHn];
    __shared__ float  b2_lds[DHOn];

    const int b   = blockIdx.x;   // batch on x: the 8 head-blocks of a batch share an XCD
    const int h   = blockIdx.y;
    const int tid = threadIdx.x;
    const int wid = tid >> 6, lane = tid & 63;
    const int lhi = lane >> 4, llo = lane & 15;
    const int rb1 = (wid >> 2) * 64;   // GEMM1 row base (waves 0-3: rows 0-63, 4-7: 64-127)
    const int cb1 = (wid & 3) * 16;    // GEMM1 col base (n)
    const int ob  = wid * 16;          // GEMM2 col base (o)
    const float NEG_INF = -__builtin_inff();

    // once-per-block: stage w2t[h] into LDS, load biases
    for (int c = tid; c < DHOn * 16; c += 512) {
        int o = c >> 4, col0 = (c & 15) * 4;
        s16x4 v = *(const s16x4*)(w2t + (h * DHOn + o) * 64 + col0);
        *(s16x4*)&w2_lds[swz(o, col0)] = v;
    }
    if (tid < DHn) b1_lds[tid] = b1[h * DHn + tid];
    else if (tid >= 64 && tid < 64 + DHOn) b2_lds[tid - 64] = b2[h * DHOn + tid - 64];
    __syncthreads();

    const float bias1 = b1_lds[cb1 + llo];
    const float bias2 = b2_lds[ob + llo];

    // online-softmax running state per score column (col = ob+llo, replicated
    // over the 4 lane-groups; l/acc are per-lane partials over owned rows)
    float m_run = NEG_INF, l_run = 0.f, a_run = 0.f;

    for (int t = 0; t < NTILE; ++t) {
        const int s0 = t * ST;
        f32x4 acc1[4];
        #pragma unroll
        for (int mf = 0; mf < 4; ++mf) acc1[mf] = {0.f, 0.f, 0.f, 0.f};

        for (int ks = 0; ks < NKS; ++ks) {
            // ---- stage A (feat f32 -> bf16) ----
            #pragma unroll
            for (int tt = 0; tt < 4; ++tt) {
                int c = tt * 512 + tid;
                int row = c >> 4, col0 = (c & 15) * 4;
                const float* gp = feat + ((size_t)(b * Sn + s0 + row)) * Dn + ks * BK + col0;
                float4 v = *(const float4*)gp;
                union { s16x4 s4; __hip_bfloat162 h2[2]; } u;
                u.h2[0] = __float22bfloat162_rn(make_float2(v.x, v.y));
                u.h2[1] = __float22bfloat162_rn(make_float2(v.z, v.w));
                *(s16x4*)&a_lds[swz(row, col0)] = u.s4;
                int pks = ks - h * 2;  // the 2 k-steps covering this head's pooled cols
                if (pks == 0 || pks == 1) {
                    *(s16x4*)&pool_lds[row * 132 + pks * 64 + col0] = u.s4;
                }
            }
            // ---- stage B (w1t slice, already bf16) ----
            #pragma unroll
            for (int tt = 0; tt < 2; ++tt) {
                int c = tt * 512 + tid;
                int n = c >> 4, col0 = (c & 15) * 4;
                s16x4 v = *(const s16x4*)(w1t + (h * DHn + n) * Dn + ks * BK + col0);
                *(s16x4*)&b_lds[swz(n, col0)] = v;
            }
            if (ks == 0 && tid < ST) mask_lds[tid] = mask[b * Sn + s0 + tid];
            __syncthreads();

            // ---- GEMM1: A[s,k] x B[k,n] ----
            s16x8 bf0 = *(s16x8*)&b_lds[swz(cb1 + llo, lhi * 8)];
            s16x8 bf1 = *(s16x8*)&b_lds[swz(cb1 + llo, 32 + lhi * 8)];
            #pragma unroll
            for (int mf = 0; mf < 4; ++mf) {
                int ar = rb1 + mf * 16 + llo;
                s16x8 a0 = *(s16x8*)&a_lds[swz(ar, lhi * 8)];
                s16x8 a1 = *(s16x8*)&a_lds[swz(ar, 32 + lhi * 8)];
                acc1[mf] = __builtin_amdgcn_mfma_f32_16x16x32_bf16(a0, bf0, acc1[mf], 0, 0, 0);
                acc1[mf] = __builtin_amdgcn_mfma_f32_16x16x32_bf16(a1, bf1, acc1[mf], 0, 0, 0);
            }
            __syncthreads();
        }

        // ---- bias + exact GELU -> h_lds (bf16) ----
        #pragma unroll
        for (int mf = 0; mf < 4; ++mf) {
            #pragma unroll
            for (int r = 0; r < 4; ++r) {
                float x = acc1[mf][r] + bias1;
                float g = 0.5f * x * (1.0f + erff(x * 0.70710678118654752f));
                int row = rb1 + mf * 16 + lhi * 4 + r;  // C-frag: row=(l>>4)*4+r, col=l&15
                h_lds[swz(row, cb1 + llo)] = f2bf(g);
            }
        }
        __syncthreads();

        // ---- GEMM2: h[s,64] x w2[64,o] -> scores [128 x 128], wave owns 16 o-cols ----
        f32x4 acc2[8];
        #pragma unroll
        for (int mf = 0; mf < 8; ++mf) acc2[mf] = {0.f, 0.f, 0.f, 0.f};
        #pragma unroll
        for (int kk = 0; kk < 2; ++kk) {
            s16x8 bfr = *(s16x8*)&w2_lds[swz(ob + llo, kk * 32 + lhi * 8)];
            #pragma unroll
            for (int mf = 0; mf < 8; ++mf) {
                s16x8 af = *(s16x8*)&h_lds[swz(mf * 16 + llo, kk * 32 + lhi * 8)];
                acc2[mf] = __builtin_amdgcn_mfma_f32_16x16x32_bf16(af, bfr, acc2[mf], 0, 0, 0);
            }
        }

        // ---- online softmax over s + pooled accumulation ----
        float sv[8][4];
        float tmax = NEG_INF;
        #pragma unroll
        for (int mf = 0; mf < 8; ++mf) {
            #pragma unroll
            for (int r = 0; r < 4; ++r) {
                int row = mf * 16 + lhi * 4 + r;
                float v = acc2[mf][r] + bias2;
                v = (mask_lds[row] == 0) ? -1e19f : v;
                sv[mf][r] = v;
                tmax = fmaxf(tmax, v);
            }
        }
        tmax = fmaxf(tmax, __shfl_xor(tmax, 16, 64));
        tmax = fmaxf(tmax, __shfl_xor(tmax, 32, 64));
        float mn = fmaxf(m_run, tmax);
        float sc = expf(m_run - mn);   // first tile: exp(-inf)=0
        l_run *= sc;
        a_run *= sc;
        #pragma unroll
        for (int mf = 0; mf < 8; ++mf) {
            #pragma unroll
            for (int r = 0; r < 4; ++r) {
                int row = mf * 16 + lhi * 4 + r;
                float p = expf(sv[mf][r] - mn);
                l_run += p;
                a_run += p * bf2f(pool_lds[row * 132 + ob + llo]);
            }
        }
        m_run = mn;
        __syncthreads();  // protect mask/pool/a_lds before next tile's staging
    }

    // finalize: sum partials across the 4 lane-groups, write pooled
    a_run += __shfl_xor(a_run, 16, 64);
    a_run += __shfl_xor(a_run, 32, 64);
    l_run += __shfl_xor(l_run, 16, 64);
    l_run += __shfl_xor(l_run, 32, 64);
    if (lane < 16) out[b * Dn + h * DHOn + ob + llo] = a_run / l_run;
}

extern "C" void kernel_launch(void* const* d_in, const int* in_sizes, int n_in,
                              void* d_out, int out_size, void* d_ws, size_t ws_size,
                              hipStream_t stream) {
    const float* feat = (const float*)d_in[0];
    const int*   mask = (const int*)d_in[1];
    // d_in[2] = lengths (unused by reference forward)
    const float* w1 = (const float*)d_in[3];
    const float* b1 = (const float*)d_in[4];
    const float* w2 = (const float*)d_in[5];
    const float* b2 = (const float*)d_in[6];
    float* out = (float*)d_out;

    ushort* w1t = (ushort*)d_ws;                                    // 8*64*1024*2 = 1 MB
    ushort* w2t = (ushort*)((char*)d_ws + (size_t)Hn * DHn * Dn * 2); // +128 KB

    hipLaunchKernelGGL(prep_w, dim3(2048), dim3(256), 0, stream, w1, w2, w1t, w2t);
    hipLaunchKernelGGL(attn_pool, dim3(Bn, Hn), dim3(512), 0, stream,
                       feat, mask, w1t, w2t, b1, b2, out);
}

// Round 2
// 863.932 us; speedup vs baseline: 1.1296x; 1.1296x over previous
//
#include <hip/hip_runtime.h>
#include <hip/hip_bf16.h>

#define Bn 32
#define Sn 2048
#define Dn 1024
#define Hn 8
#define DHn 64
#define DHOn 128
#define ST 128          // rows per s-tile
#define SC 256          // rows per block (2 tiles)
#define NSC 8           // S-chunks = Sn/SC

typedef __attribute__((ext_vector_type(8))) short s16x8;
typedef __attribute__((ext_vector_type(4))) short s16x4;
typedef __attribute__((ext_vector_type(4))) float f32x4;

// element-index swizzle for row-major [rows][64] bf16 tiles (breaks the
// 16-way bank conflict of 128B-stride column reads; same XOR on write+read)
__device__ __forceinline__ int swz(int row, int col) {
    return row * 64 + (col ^ ((row & 7) << 3));
}
__device__ __forceinline__ ushort f2bf(float x) {
    union { float f; unsigned int u; } v; v.f = x;
    unsigned int r = v.u + 0x7fffu + ((v.u >> 16) & 1u);
    return (ushort)(r >> 16);
}

// Pre-pack weights into MFMA fragment order (bf16):
// w1f[h][ks][p][lane][j]: p = nt*2+kh; value = w1[h][ks*64+kh*32+(lane>>4)*8+j][nt*16+(lane&15)]
// w2f[h][q][lane][j]:     q = ot*2+kh; value = w2[h][kh*32+(lane>>4)*8+j][ot*16+(lane&15)]
__global__ void prep_w(const float* __restrict__ w1, const float* __restrict__ w2,
                       ushort* __restrict__ w1f, ushort* __restrict__ w2f) {
    int idx = blockIdx.x * 256 + threadIdx.x;
    if (idx < Hn * 16 * 8 * 64 * 8) {           // 524288
        int j  = idx & 7;
        int l  = (idx >> 3) & 63;
        int p  = (idx >> 9) & 7;
        int ks = (idx >> 12) & 15;
        int h  = idx >> 16;
        int nt = p >> 1, kh = p & 1;
        int k  = ks * 64 + kh * 32 + (l >> 4) * 8 + j;
        int n  = nt * 16 + (l & 15);
        w1f[idx] = f2bf(w1[(h * Dn + k) * DHn + n]);
    }
    if (idx < Hn * 16 * 64 * 8) {               // 65536
        int j = idx & 7;
        int l = (idx >> 3) & 63;
        int q = (idx >> 9) & 15;
        int h = idx >> 13;
        int ot = q >> 1, kh = q & 1;
        int k = kh * 32 + (l >> 4) * 8 + j;
        int o = ot * 16 + (l & 15);
        w2f[idx] = f2bf(w2[(h * DHn + k) * DHOn + o]);
    }
}

__global__ __launch_bounds__(512, 2)
void attn_pool(const float* __restrict__ feat, const int* __restrict__ mask,
               const ushort* __restrict__ w1f, const ushort* __restrict__ w2f,
               const float* __restrict__ b1, const float* __restrict__ b2,
               float* __restrict__ pm, float* __restrict__ pl, float* __restrict__ pa) {
    __shared__ ushort a_lds[ST * 64];        // feat tile [s][k] bf16, swizzled (shared)
    __shared__ ushort h_lds[Hn][ST * 64];    // per-wave gelu(h) [s][n] bf16, swizzled
    __shared__ int    mask_lds[SC];

    const int sc  = blockIdx.x;              // S-chunk
    const int b   = blockIdx.y;              // batch
    const int tid = threadIdx.x;
    const int wid = tid >> 6, lane = tid & 63;
    const int lhi = lane >> 4, llo = lane & 15;
    const int h   = wid;                     // wave == head
    const int srow = tid >> 4;               // staging: row base 0..31
    const int scol = (tid & 15) * 4;         // staging: col 0..60

    const float* fb = feat + ((size_t)(b * Sn + sc * SC)) * Dn;

    float bias1[4], bias2[8];
    #pragma unroll
    for (int nt = 0; nt < 4; ++nt) bias1[nt] = b1[h * DHn + nt * 16 + llo];
    #pragma unroll
    for (int ci = 0; ci < 8; ++ci) bias2[ci] = b2[h * DHOn + ci * 16 + llo];

    // online-softmax running state: 8 o-tiles/lane (col = ci*16+llo), partial over
    // this lane's 32 rows per tile (rows split across the 4 lhi groups)
    float sm[8], sl[8], sa[8];
    #pragma unroll
    for (int ci = 0; ci < 8; ++ci) { sm[ci] = -3.0e38f; sl[ci] = 0.f; sa[ci] = 0.f; }

    if (tid < SC) mask_lds[tid] = mask[b * Sn + sc * SC + tid];

    // prologue: stage tile t=0, ks=0
    #pragma unroll
    for (int tt = 0; tt < 4; ++tt) {
        float4 v = *(const float4*)(fb + (size_t)(srow + tt * 32) * Dn + scol);
        union { s16x4 s4; __hip_bfloat162 h2[2]; } u;
        u.h2[0] = __float22bfloat162_rn(make_float2(v.x, v.y));
        u.h2[1] = __float22bfloat162_rn(make_float2(v.z, v.w));
        *(s16x4*)&a_lds[swz(srow + tt * 32, scol)] = u.s4;
    }
    __syncthreads();

    for (int t = 0; t < 2; ++t) {
        f32x4 acc1[8][4];
        #pragma unroll
        for (int mt = 0; mt < 8; ++mt)
            #pragma unroll
            for (int nt = 0; nt < 4; ++nt) acc1[mt][nt] = (f32x4){0.f, 0.f, 0.f, 0.f};

        for (int ks = 0; ks < 16; ++ks) {
            const int gn = t * 16 + ks + 1;          // next global k-step
            float4 nreg[4];
            if (gn < 32) {
                const float* src = fb + (size_t)((gn >> 4) * ST) * Dn + (gn & 15) * 64 + scol;
                #pragma unroll
                for (int tt = 0; tt < 4; ++tt)
                    nreg[tt] = *(const float4*)(src + (size_t)(srow + tt * 32) * Dn);
            }
            // B fragments for (head, ks): fully-coalesced 16B/lane reads (L2-resident)
            const ushort* wb = w1f + (size_t)((h * 16 + ks) * 8) * 512 + lane * 8;
            s16x8 bf[8];
            #pragma unroll
            for (int p = 0; p < 8; ++p) bf[p] = *(const s16x8*)(wb + p * 512);
            // GEMM1 MFMAs: 8 mt x 4 nt x 2 kh
            #pragma unroll
            for (int mt = 0; mt < 8; ++mt) {
                s16x8 a0 = *(const s16x8*)&a_lds[swz(mt * 16 + llo, lhi * 8)];
                s16x8 a1 = *(const s16x8*)&a_lds[swz(mt * 16 + llo, 32 + lhi * 8)];
                #pragma unroll
                for (int nt = 0; nt < 4; ++nt) {
                    acc1[mt][nt] = __builtin_amdgcn_mfma_f32_16x16x32_bf16(a0, bf[nt * 2 + 0], acc1[mt][nt], 0, 0, 0);
                    acc1[mt][nt] = __builtin_amdgcn_mfma_f32_16x16x32_bf16(a1, bf[nt * 2 + 1], acc1[mt][nt], 0, 0, 0);
                }
            }
            if (gn < 32) {
                __syncthreads();
                #pragma unroll
                for (int tt = 0; tt < 4; ++tt) {
                    union { s16x4 s4; __hip_bfloat162 h2[2]; } u;
                    u.h2[0] = __float22bfloat162_rn(make_float2(nreg[tt].x, nreg[tt].y));
                    u.h2[1] = __float22bfloat162_rn(make_float2(nreg[tt].z, nreg[tt].w));
                    *(s16x4*)&a_lds[swz(srow + tt * 32, scol)] = u.s4;
                }
                __syncthreads();
            }
        }

        // ---- epilogue for tile t (wave-private; no barriers needed) ----
        ushort* hw = &h_lds[wid][0];
        #pragma unroll
        for (int mt = 0; mt < 8; ++mt)
            #pragma unroll
            for (int nt = 0; nt < 4; ++nt) {
                f32x4 aa = acc1[mt][nt];
                #pragma unroll
                for (int r = 0; r < 4; ++r) {
                    float x = aa[r] + bias1[nt];
                    float gl = 0.5f * x * (1.0f + erff(x * 0.70710678118654752f));
                    hw[swz(mt * 16 + lhi * 4 + r, nt * 16 + llo)] = f2bf(gl);
                }
            }

        const int srow0 = t * ST;
        const float* pbase = fb + (size_t)srow0 * Dn + h * DHOn;   // pooled feature cols
        #pragma unroll
        for (int c = 0; c < 4; ++c) {
            f32x4 acc2[8][2];
            #pragma unroll
            for (int mt = 0; mt < 8; ++mt) {
                acc2[mt][0] = (f32x4){0.f, 0.f, 0.f, 0.f};
                acc2[mt][1] = (f32x4){0.f, 0.f, 0.f, 0.f};
            }
            s16x8 wf[2][2];
            #pragma unroll
            for (int n2 = 0; n2 < 2; ++n2)
                #pragma unroll
                for (int kh = 0; kh < 2; ++kh) {
                    int q = (c * 2 + n2) * 2 + kh;
                    wf[n2][kh] = *(const s16x8*)(w2f + (size_t)((h * 16 + q) * 64 + lane) * 8);
                }
            #pragma unroll
            for (int mt = 0; mt < 8; ++mt) {
                s16x8 h0 = *(const s16x8*)&hw[swz(mt * 16 + llo, lhi * 8)];
                s16x8 h1 = *(const s16x8*)&hw[swz(mt * 16 + llo, 32 + lhi * 8)];
                #pragma unroll
                for (int n2 = 0; n2 < 2; ++n2) {
                    acc2[mt][n2] = __builtin_amdgcn_mfma_f32_16x16x32_bf16(h0, wf[n2][0], acc2[mt][n2], 0, 0, 0);
                    acc2[mt][n2] = __builtin_amdgcn_mfma_f32_16x16x32_bf16(h1, wf[n2][1], acc2[mt][n2], 0, 0, 0);
                }
            }
            #pragma unroll
            for (int n2 = 0; n2 < 2; ++n2) {
                const int ci = c * 2 + n2;
                float v[8][4];
                float tmax = -3.0e38f;
                #pragma unroll
                for (int mt = 0; mt < 8; ++mt)
                    #pragma unroll
                    for (int r = 0; r < 4; ++r) {
                        int row = mt * 16 + lhi * 4 + r;
                        float x = acc2[mt][n2][r] + bias2[ci];
                        x = (mask_lds[srow0 + row] == 0) ? -1e19f : x;
                        v[mt][r] = x;
                        tmax = fmaxf(tmax, x);
                    }
                float mn = fmaxf(sm[ci], tmax);
                float scale = __expf(sm[ci] - mn);
                sl[ci] *= scale;
                sa[ci] *= scale;
                const float* pc = pbase + ci * 16 + llo;
                #pragma unroll
                for (int mt = 0; mt < 8; ++mt)
                    #pragma unroll
                    for (int r = 0; r < 4; ++r) {
                        float p = __expf(v[mt][r] - mn);
                        sl[ci] += p;
                        sa[ci] += p * pc[(size_t)(mt * 16 + lhi * 4 + r) * Dn];
                    }
                sm[ci] = mn;
            }
        }
    }

    // merge the 4 lhi row-groups (xor 16, then 32)
    #pragma unroll
    for (int ci = 0; ci < 8; ++ci) {
        {
            float m2 = __shfl_xor(sm[ci], 16, 64);
            float l2 = __shfl_xor(sl[ci], 16, 64);
            float a2 = __shfl_xor(sa[ci], 16, 64);
            float mn = fmaxf(sm[ci], m2);
            float e1 = __expf(sm[ci] - mn), e2 = __expf(m2 - mn);
            sl[ci] = sl[ci] * e1 + l2 * e2;
            sa[ci] = sa[ci] * e1 + a2 * e2;
            sm[ci] = mn;
        }
        {
            float m2 = __shfl_xor(sm[ci], 32, 64);
            float l2 = __shfl_xor(sl[ci], 32, 64);
            float a2 = __shfl_xor(sa[ci], 32, 64);
            float mn = fmaxf(sm[ci], m2);
            float e1 = __expf(sm[ci] - mn), e2 = __expf(m2 - mn);
            sl[ci] = sl[ci] * e1 + l2 * e2;
            sa[ci] = sa[ci] * e1 + a2 * e2;
            sm[ci] = mn;
        }
    }
    if (lane < 16) {
        size_t base = ((size_t)((b * NSC + sc) * Hn + h)) * DHOn;
        #pragma unroll
        for (int ci = 0; ci < 8; ++ci) {
            int o = ci * 16 + llo;
            pm[base + o] = sm[ci];
            pl[base + o] = sl[ci];
            pa[base + o] = sa[ci];
        }
    }
}

// combine the 8 S-chunk partials per (b, h, o)
__global__ void combine(const float* __restrict__ pm, const float* __restrict__ pl,
                        const float* __restrict__ pa, float* __restrict__ out) {
    int idx = blockIdx.x * 256 + threadIdx.x;
    if (idx >= Bn * Dn) return;
    int b  = idx >> 10;
    int ho = idx & 1023;
    int hh = ho >> 7, o = ho & 127;
    float m = -3.0e38f, l = 0.f, a = 0.f;
    for (int sc = 0; sc < NSC; ++sc) {
        size_t i = ((size_t)((b * NSC + sc) * Hn + hh)) * DHOn + o;
        float mi = pm[i], li = pl[i], ai = pa[i];
        float mn = fmaxf(m, mi);
        float e1 = __expf(m - mn), e2 = __expf(mi - mn);
        l = l * e1 + li * e2;
        a = a * e1 + ai * e2;
        m = mn;
    }
    out[idx] = a / l;
}

extern "C" void kernel_launch(void* const* d_in, const int* in_sizes, int n_in,
                              void* d_out, int out_size, void* d_ws, size_t ws_size,
                              hipStream_t stream) {
    const float* feat = (const float*)d_in[0];
    const int*   mask = (const int*)d_in[1];
    // d_in[2] = lengths (unused by reference forward)
    const float* w1 = (const float*)d_in[3];
    const float* b1 = (const float*)d_in[4];
    const float* w2 = (const float*)d_in[5];
    const float* b2 = (const float*)d_in[6];
    float* out = (float*)d_out;

    ushort* w1f = (ushort*)d_ws;                         // 524288 bf16 = 1 MB
    ushort* w2f = w1f + 524288;                          // 65536 bf16 = 128 KB
    float*  pm  = (float*)((char*)d_ws + (1u << 20) + (128u << 10));
    float*  pl  = pm + Bn * NSC * Hn * DHOn;             // 262144 floats each
    float*  pa  = pl + Bn * NSC * Hn * DHOn;

    hipLaunchKernelGGL(prep_w, dim3(2048), dim3(256), 0, stream, w1, w2, w1f, w2f);
    hipLaunchKernelGGL(attn_pool, dim3(NSC, Bn), dim3(512), 0, stream,
                       feat, mask, w1f, w2f, b1, b2, pm, pl, pa);
    hipLaunchKernelGGL(combine, dim3((Bn * Dn + 255) / 256), dim3(256), 0, stream,
                       pm, pl, pa, out);
}